// Round 3
// baseline (11463.419 us; speedup 1.0000x reference)
//
#include <hip/hip_runtime.h>
#include <stdint.h>

// One block per sample. All intermediates in a liveness-packed LDS pool.
// LDS layout (floats), schedule order: x -> z0a -> z0sl -> t90 -> x1 -> t2 ->
// z1 -> z1s -> x2 -> t3 -> z2 -> z2s -> out(global)
//   SX  [0,135)      live steps 1-5
//   Z0A [160,835)    steps 2-3
//   Z0SL[840,1340)   (5c,5h,18o) stride 20, steps 3-4
//   T90 [1340,1430)  steps 5-4'
//   X1  [1440,3940)  (25c,5h,18) stride 20, steps 4'-8
//   T2  [3940,5440)  (25c,5h,10) stride 12, steps 7-10'
//   Z1  [5440,11440) (75,4,18) stride 20, steps 8-9
//   Z1S [0,3600)     (75,4,10) stride 12, steps 9-10'   (reuses dead SX..X1)
//   X2  [5440,9940)  (125,3,10) stride 12, steps 10'-13 (reuses dead Z1)
//   T3  [0,3000)     (125,3,5) stride 8, steps 12-15    (reuses dead Z1S)
//   Z2  [9940,15940) (300,2,10) stride 10, steps 13-14
//   Z2S [3000,7800)  (300,2,5) stride 8, steps 14-15    (reuses dead T2/X2)
// pool = 15944 floats = 63776 B  -> 2 blocks/CU

__global__ __launch_bounds__(256, 2)
void fused_net(const float* __restrict__ xg,
  const float* __restrict__ w0a_, const float* __restrict__ b0a_,
  const float* __restrict__ wl0_, const float* __restrict__ bl0_,
  const float* __restrict__ w0b_, const float* __restrict__ b0b_,
  const float* __restrict__ w0c_, const float* __restrict__ b0c_,
  const float* __restrict__ wr0_, const float* __restrict__ br0_,
  const float* __restrict__ w1_,  const float* __restrict__ b1_,
  const float* __restrict__ wl1_, const float* __restrict__ bl1_,
  const float* __restrict__ w2_,  const float* __restrict__ b2_,
  const float* __restrict__ wa_,  const float* __restrict__ ba_,
  const float* __restrict__ wra_, const float* __restrict__ bra_,
  const float* __restrict__ w0_,  const float* __restrict__ b0_,
  const float* __restrict__ wl2_, const float* __restrict__ bl2_,
  const float* __restrict__ w0b2_,const float* __restrict__ b0b2_,
  const float* __restrict__ w0c2_,const float* __restrict__ b0c2_,
  const float* __restrict__ wr02_,const float* __restrict__ br02_,
  float* __restrict__ outg)
{
  __shared__ float S[15944];
  const int tid = threadIdx.x;
  const int b = blockIdx.x;

  float* SX  = S + 0;
  float* Z0A = S + 160;
  float* Z0SL= S + 840;
  float* T90 = S + 1340;
  float* X1  = S + 1440;
  float* T2  = S + 3940;
  float* Z1  = S + 5440;
  float* Z1S = S + 0;
  float* X2  = S + 5440;
  float* T3  = S + 0;
  float* Z2  = S + 9940;
  float* Z2S = S + 3000;

  // 1. load x (B,1,5,27)
  const float* xb = xg + (size_t)b * 135;
  for (int i = tid; i < 135; i += 256) SX[i] = xb[i];
  __syncthreads();

  // 2. z0a = conv w0a (1->5ch, kh=3, pad 1) : (5co,5h,27w)
  for (int i = tid; i < 675; i += 256) {
    int co = i / 135, r = i % 135, h = r / 27, w = r % 27;
    float acc = b0a_[co];
    #pragma unroll
    for (int dh = 0; dh < 3; ++dh) {
      int hi = h + dh - 1;
      if (hi >= 0 && hi < 5) acc += SX[hi*27 + w] * w0a_[co*3 + dh];
    }
    Z0A[i] = acc;   // i == (co*5+h)*27+w
  }
  __syncthreads();

  // 3. z0sl = relu(sl(z0a, wl0)) : (5c,5h,18o) stride 20
  for (int i = tid; i < 450; i += 256) {
    int c = i / 90, r = i % 90, h = r / 18, o = r % 18;
    float acc = bl0_[o];
    const float* row = Z0A + (c*5 + h)*27;
    for (int w = 0; w < 27; ++w) acc += row[w] * wl0_[o*27 + w];
    Z0SL[(c*5 + h)*20 + o] = fmaxf(acc, 0.f);
  }
  __syncthreads();

  // 5. t90 = sl(x, wr0) : (5h,18o)
  for (int i = tid; i < 90; i += 256) {
    int h = i / 18, o = i % 18;
    float acc = br0_[o];
    const float* row = SX + h*27;
    for (int w = 0; w < 27; ++w) acc += row[w] * wr0_[o*27 + w];
    T90[i] = acc;
  }
  __syncthreads();

  // 4'. x1 = conv w0b(z0sl) + b0b + (w0c * t90 + b0c) : (25co,5h,18o) stride 20
  for (int i = tid; i < 2250; i += 256) {
    int co = i / 90, r = i % 90, h = r / 18, o = r % 18;
    float acc = b0b_[co] + b0c_[co] + T90[h*18 + o] * w0c_[co];
    #pragma unroll
    for (int dh = 0; dh < 3; ++dh) {
      int hi = h + dh - 1;
      if (hi >= 0 && hi < 5) {
        #pragma unroll
        for (int ci = 0; ci < 5; ++ci)
          acc += Z0SL[(ci*5 + hi)*20 + o] * w0b_[(co*5 + ci)*3 + dh];
      }
    }
    X1[(co*5 + h)*20 + o] = acc;
  }
  __syncthreads();

  // 7. t2 = sl(x1, wra) : (25c,5h,10o) stride 12
  for (int i = tid; i < 1250; i += 256) {
    int c = i / 50, r = i % 50, h = r / 10, o = r % 10;
    float acc = bra_[o];
    const float* row = X1 + (c*5 + h)*20;
    for (int w = 0; w < 18; ++w) acc += row[w] * wra_[o*18 + w];
    T2[(c*5 + h)*12 + o] = acc;
  }
  __syncthreads();

  // 8. z1 = conv w1(x1) (25->75, kh=2) : (75co,4h,18w) stride 20
  for (int task = tid; task < 300; task += 256) {
    int co = task / 4, h = task % 4;
    float acc[18];
    float bias = b1_[co];
    #pragma unroll
    for (int w = 0; w < 18; ++w) acc[w] = bias;
    for (int ci = 0; ci < 25; ++ci) {
      float wx = w1_[(co*25 + ci)*2 + 0];
      float wy = w1_[(co*25 + ci)*2 + 1];
      const float* r0 = X1 + (ci*5 + h)*20;
      #pragma unroll
      for (int w = 0; w < 18; ++w) acc[w] += r0[w]*wx + r0[20 + w]*wy;
    }
    float* orow = Z1 + (co*4 + h)*20;
    #pragma unroll
    for (int w = 0; w < 18; ++w) orow[w] = acc[w];
  }
  __syncthreads();

  // 9. z1s = relu(sl(z1, wl1)) : (75c,4h,10o) stride 12
  for (int i = tid; i < 3000; i += 256) {
    int c = i / 40, r = i % 40, h = r / 10, o = r % 10;
    float acc = bl1_[o];
    const float* row = Z1 + (c*4 + h)*20;
    for (int w = 0; w < 18; ++w) acc += row[w] * wl1_[o*18 + w];
    Z1S[(c*4 + h)*12 + o] = fmaxf(acc, 0.f);
  }
  __syncthreads();

  // 10'. x2 = conv w2(z1s) + conv wa(t2) : (125co,3h,10w) stride 12
  for (int task = tid; task < 375; task += 256) {
    int co = task / 3, h = task % 3;
    float acc[10];
    float bias = b2_[co] + ba_[co];
    #pragma unroll
    for (int w = 0; w < 10; ++w) acc[w] = bias;
    for (int ci = 0; ci < 75; ++ci) {          // w2: kh=2
      float wx = w2_[(co*75 + ci)*2 + 0];
      float wy = w2_[(co*75 + ci)*2 + 1];
      const float* r0 = Z1S + (ci*4 + h)*12;
      #pragma unroll
      for (int w = 0; w < 10; ++w) acc[w] += r0[w]*wx + r0[12 + w]*wy;
    }
    for (int ci = 0; ci < 25; ++ci) {          // wa: kh=3
      float wf0 = wa_[(co*25 + ci)*3 + 0];
      float wf1 = wa_[(co*25 + ci)*3 + 1];
      float wf2 = wa_[(co*25 + ci)*3 + 2];
      const float* r0 = T2 + (ci*5 + h)*12;
      #pragma unroll
      for (int w = 0; w < 10; ++w)
        acc[w] += r0[w]*wf0 + r0[12 + w]*wf1 + r0[24 + w]*wf2;
    }
    float* orow = X2 + (co*3 + h)*12;
    #pragma unroll
    for (int w = 0; w < 10; ++w) orow[w] = acc[w];
  }
  __syncthreads();

  // 12. t3 = sl(x2, wr02) : (125c,3h,5o) stride 8
  for (int i = tid; i < 1875; i += 256) {
    int c = i / 15, r = i % 15, h = r / 5, o = r % 5;
    float acc = br02_[o];
    const float* row = X2 + (c*3 + h)*12;
    for (int w = 0; w < 10; ++w) acc += row[w] * wr02_[o*10 + w];
    T3[(c*3 + h)*8 + o] = acc;
  }
  __syncthreads();

  // 13. z2 = conv w0(x2) (125->300, kh=2) : (300co,2h,10w) stride 10
  //     one thread per co, both h outputs (middle row shared)
  for (int co = tid; co < 300; co += 256) {
    float acc0[10], acc1[10];
    float bias = b0_[co];
    #pragma unroll
    for (int w = 0; w < 10; ++w) { acc0[w] = bias; acc1[w] = bias; }
    for (int ci = 0; ci < 125; ++ci) {
      float wx = w0_[(co*125 + ci)*2 + 0];
      float wy = w0_[(co*125 + ci)*2 + 1];
      const float* r0 = X2 + ci*36;   // rows h=0,1,2 at +0,+12,+24
      #pragma unroll
      for (int w = 0; w < 10; ++w) {
        float a0 = r0[w], a1 = r0[12 + w], a2 = r0[24 + w];
        acc0[w] += a0*wx + a1*wy;
        acc1[w] += a1*wx + a2*wy;
      }
    }
    float* o0 = Z2 + (co*2)*10;
    #pragma unroll
    for (int w = 0; w < 10; ++w) { o0[w] = acc0[w]; o0[10 + w] = acc1[w]; }
  }
  __syncthreads();

  // 14. z2s = relu(sl(z2, wl2)) : (300c,2h,5o) stride 8
  for (int i = tid; i < 3000; i += 256) {
    int c = i / 10, r = i % 10, h = r / 5, o = r % 5;
    float acc = bl2_[o];
    const float* row = Z2 + (c*2 + h)*10;
    for (int w = 0; w < 10; ++w) acc += row[w] * wl2_[o*10 + w];
    Z2S[(c*2 + h)*8 + o] = fmaxf(acc, 0.f);
  }
  __syncthreads();

  // 15'. out = conv w0b2(z2s) + conv w0c2(t3) : (512co,1,5w) -> global fp32
  //      one thread handles co and co+256 (activation reads shared)
  float* ob = outg + (size_t)b * 2560;
  {
    const int co0 = tid, co1 = tid + 256;
    float acc[2][5];
    acc[0][0] = b0b2_[co0] + b0c2_[co0];
    acc[1][0] = b0b2_[co1] + b0c2_[co1];
    #pragma unroll
    for (int w = 1; w < 5; ++w) { acc[0][w] = acc[0][0]; acc[1][w] = acc[1][0]; }
    for (int ci = 0; ci < 300; ++ci) {         // w0b2: kh=2
      float w0x = w0b2_[(co0*300 + ci)*2 + 0];
      float w0y = w0b2_[(co0*300 + ci)*2 + 1];
      float w1x = w0b2_[(co1*300 + ci)*2 + 0];
      float w1y = w0b2_[(co1*300 + ci)*2 + 1];
      const float* r0 = Z2S + ci*16;
      #pragma unroll
      for (int w = 0; w < 5; ++w) {
        float a = r0[w], c2 = r0[8 + w];
        acc[0][w] += a*w0x + c2*w0y;
        acc[1][w] += a*w1x + c2*w1y;
      }
    }
    for (int ci = 0; ci < 125; ++ci) {         // w0c2: kh=3
      float u0 = w0c2_[(co0*125 + ci)*3 + 0];
      float u1 = w0c2_[(co0*125 + ci)*3 + 1];
      float u2 = w0c2_[(co0*125 + ci)*3 + 2];
      float v0 = w0c2_[(co1*125 + ci)*3 + 0];
      float v1 = w0c2_[(co1*125 + ci)*3 + 1];
      float v2 = w0c2_[(co1*125 + ci)*3 + 2];
      const float* r0 = T3 + ci*24;
      #pragma unroll
      for (int w = 0; w < 5; ++w) {
        float a = r0[w], c2 = r0[8 + w], e = r0[16 + w];
        acc[0][w] += a*u0 + c2*u1 + e*u2;
        acc[1][w] += a*v0 + c2*v1 + e*v2;
      }
    }
    #pragma unroll
    for (int w = 0; w < 5; ++w) {
      ob[co0*5 + w] = acc[0][w];
      ob[co1*5 + w] = acc[1][w];
    }
  }
}

extern "C" void kernel_launch(void* const* d_in, const int* in_sizes, int n_in,
                              void* d_out, int out_size, void* d_ws, size_t ws_size,
                              hipStream_t stream) {
  (void)in_sizes; (void)n_in; (void)d_ws; (void)ws_size;
  const float* p[31];
  for (int i = 0; i < 31; ++i) p[i] = (const float*)d_in[i];
  int B = out_size / 2560;   // (512*1*5) per sample
  fused_net<<<B, 256, 0, stream>>>(
      p[0],
      p[1],  p[2],  p[3],  p[4],  p[5],  p[6],  p[7],  p[8],  p[9],  p[10],
      p[11], p[12], p[13], p[14], p[15], p[16], p[17], p[18], p[19], p[20],
      p[21], p[22], p[23], p[24], p[25], p[26], p[27], p[28], p[29], p[30],
      (float*)d_out);
}